// Round 19
// baseline (144.890 us; speedup 1.0000x reference)
//
#include <hip/hip_runtime.h>

#define EPSV 1e-5f
typedef unsigned short u16;
typedef unsigned int u32;

// Problem constants: B=4, N=8, B2=32, C=128, H=W=64, HW=4096, KS=3
// Workspace (float offsets):
//   [0,        8388608)  xq    (u32 quad-interleaved bf16 x: [b2][c8][px][4dw])
//   [8388608, 16777216)  k2dq  (u32 quad-interleaved bf16 k2d)
//   [16777216,25165824)  vh    (u16 bf16, standard layout)
//   [25165824,33554432)  aggh  (u16 bf16, standard layout)
//   [33554432,39845888)  wdh   (u16 bf16, standard layout)
//   [39845888,39871488)  packed weights: wkF[6144] wB1[8192] wB[8192] wB2[3072]
//   stats @46137344: gnsum[1024] gnsq[1024] gap[512] ... attn @ +4608
typedef __attribute__((ext_vector_type(8))) __bf16 bf16x8;
typedef __attribute__((ext_vector_type(4))) float f32x4;
union ABcast { uint4 u; bf16x8 v; };

__device__ __forceinline__ u32 bfbits(float f) {   // RNE f32->bf16 bits
    u32 u = __float_as_uint(f);
    u += 0x7fff + ((u >> 16) & 1);
    return u >> 16;
}
__device__ __forceinline__ float bflo(u32 p) { return __uint_as_float(p << 16); }
__device__ __forceinline__ float bfhi(u32 p) { return __uint_as_float(p & 0xffff0000u); }

// ---- kXW: x -> xq (quad bf16), + weight packing (blocks 0..99), + stats zero ----
__global__ __launch_bounds__(256, 8) void kXW_cvt(
    const float* __restrict__ x, u32* __restrict__ xq,
    const float* __restrict__ wk, const float* __restrict__ w1,
    const float* __restrict__ we1, const float* __restrict__ we2,
    u32* __restrict__ wkF, u32* __restrict__ wB1,
    u32* __restrict__ wB, u32* __restrict__ wB2,
    float* __restrict__ stats_zero)
{
    int qid = blockIdx.x * 256 + threadIdx.x;
    int px  = qid & 4095;
    int c8g = qid >> 12;                        // b2*16 + c8
    const float* xp = x + (c8g * 8) * 4096 + px;
    uint4 o;
    o.x = bfbits(xp[0])        | (bfbits(xp[4096])     << 16);
    o.y = bfbits(xp[2 * 4096]) | (bfbits(xp[3 * 4096]) << 16);
    o.z = bfbits(xp[4 * 4096]) | (bfbits(xp[5 * 4096]) << 16);
    o.w = bfbits(xp[6 * 4096]) | (bfbits(xp[7 * 4096]) << 16);
    *(uint4*)(xq + (c8g * 4096 + px) * 4) = o;

    int i = qid;
    if (i < 2560) stats_zero[i] = 0.f;          // gnsum, gnsq, gap
    if (i < 6144) {                             // wkF: B-frags of w_key per (grp,dk)
        int jj = i & 3;
        int ln = (i >> 2) & 63;
        int nt = (i >> 8) & 1;
        int rest = i >> 9;
        int grp = rest / 3, dk = rest % 3;
        int n = nt * 16 + (ln & 15);
        int k = (ln >> 4) * 8 + 2 * jj;
        int oo = grp * 32 + n;
        wkF[i] = bfbits(wk[oo * 96 + k * 3 + dk]) |
                 (bfbits(wk[oo * 96 + (k + 1) * 3 + dk]) << 16);
    } else if (i < 14336) {                     // wB1: B-frags of w_1x1
        int j2 = i - 6144;
        int jj = j2 & 3;
        int ln = (j2 >> 2) & 63;
        int nt = (j2 >> 8) & 7;
        int kb = j2 >> 11;
        int n = nt * 16 + (ln & 15);
        int k = kb * 32 + (ln >> 4) * 8 + 2 * jj;
        wB1[j2] = bfbits(w1[n * 128 + k]) | (bfbits(w1[n * 128 + k + 1]) << 16);
    } else if (i < 22528) {                     // wB: B-frags of w_e1
        int j2 = i - 14336;
        int jj = j2 & 3;
        int ln = (j2 >> 2) & 63;
        int nt = (j2 >> 8) & 3;
        int kb = j2 >> 10;
        int n  = nt * 16 + (ln & 15);
        int k  = kb * 32 + (ln >> 4) * 8 + 2 * jj;
        wB[j2] = bfbits(we1[n * 256 + k]) | (bfbits(we1[n * 256 + k + 1]) << 16);
    } else if (i < 25600) {                     // wB2: B-frags of w_e2 (96x64)
        int j2 = i - 22528;
        int jj = j2 & 3;
        int ln = (j2 >> 2) & 63;
        int rest = j2 >> 8;
        int kb = rest / 6, nt = rest % 6;
        int n = nt * 16 + (ln & 15);
        int k = kb * 32 + (ln >> 4) * 8 + 2 * jj;
        wB2[j2] = bfbits(we2[n * 64 + k]) | (bfbits(we2[n * 64 + k + 1]) << 16);
    }
}

// ---- kA: key_embed via MFMA -> k2dq (quad layout via LDS repack), + gap ----
__global__ __launch_bounds__(256, 4) void kA_key(
    const u32* __restrict__ xq, const u32* __restrict__ wkF,
    const float* __restrict__ g, const float* __restrict__ bb,
    const float* __restrict__ m, const float* __restrict__ vr,
    u32* __restrict__ k2dq, float* __restrict__ gap)
{
    int tid  = threadIdx.x;
    int lane = tid & 63;
    int q    = __builtin_amdgcn_readfirstlane(tid >> 6);   // 0..3
    int blk  = blockIdx.x;
    int tile = blk & 15;
    int grp  = (blk >> 4) & 3;
    int b2   = blk >> 6;
    int px0  = tile * 256;
    int bi = b2 >> 3, ni = b2 & 7;
    int lrow = lane & 15, lk = lane >> 4;
    const uint4* wkF4 = (const uint4*)wkF;

    f32x4 acc[4][2];
    #pragma unroll
    for (int mt = 0; mt < 4; ++mt)
        #pragma unroll
        for (int nt = 0; nt < 2; ++nt)
            acc[mt][nt] = (f32x4){0.f, 0.f, 0.f, 0.f};

    int pxA[4];
    #pragma unroll
    for (int mt = 0; mt < 4; ++mt) pxA[mt] = px0 + (4 * q + mt) * 16 + lrow;

    #pragma unroll
    for (int dk = 0; dk < 3; ++dk) {
        int nf = ni + dk - 1;
        if (nf >= 0 && nf < 8) {
            const u32* src = xq + (((bi * 8 + nf) * 16 + grp * 4 + lk) * 4096) * 4;
            ABcast a[4];
            #pragma unroll
            for (int mt = 0; mt < 4; ++mt)
                a[mt].u = *(const uint4*)(src + pxA[mt] * 4);
            #pragma unroll
            for (int nt = 0; nt < 2; ++nt) {
                ABcast bfr;
                bfr.u = wkF4[((grp * 3 + dk) * 2 + nt) * 64 + lane];
                #pragma unroll
                for (int mt = 0; mt < 4; ++mt)
                    acc[mt][nt] = __builtin_amdgcn_mfma_f32_16x16x32_bf16(
                        a[mt].v, bfr.v, acc[mt][nt], 0, 0, 0);
            }
        }
    }

    __shared__ u16  karr[32][260];
    __shared__ float ssum[32][4];
    #pragma unroll
    for (int nt = 0; nt < 2; ++nt) {
        int ch = grp * 32 + nt * 16 + lrow;
        float s = g[ch] * rsqrtf(vr[ch] + EPSV);
        float t = bb[ch] - m[ch] * s;
        float lsum = 0.f;
        #pragma unroll
        for (int mt = 0; mt < 4; ++mt) {
            float r0 = fmaxf(fmaf(acc[mt][nt].x, s, t), 0.f);
            float r1 = fmaxf(fmaf(acc[mt][nt].y, s, t), 0.f);
            float r2 = fmaxf(fmaf(acc[mt][nt].z, s, t), 0.f);
            float r3 = fmaxf(fmaf(acc[mt][nt].w, s, t), 0.f);
            lsum += r0 + r1 + r2 + r3;
            int pxl = (4 * q + mt) * 16 + lk * 4;
            u16* kr = &karr[nt * 16 + lrow][pxl];
            kr[0] = (u16)bfbits(r0);
            kr[1] = (u16)bfbits(r1);
            kr[2] = (u16)bfbits(r2);
            kr[3] = (u16)bfbits(r3);
        }
        lsum += __shfl_xor(lsum, 16, 64);
        lsum += __shfl_xor(lsum, 32, 64);
        if (lane < 16) ssum[nt * 16 + lrow][q] = lsum;
    }
    __syncthreads();
    if (tid < 32) {
        float* sr = ssum[tid];
        atomicAdd(&gap[bi * 128 + grp * 32 + tid], sr[0] + sr[1] + sr[2] + sr[3]);
    }
    #pragma unroll
    for (int c8g = 0; c8g < 4; ++c8g) {
        uint4 pk;
        pk.x = (u32)karr[c8g * 8 + 0][tid] | ((u32)karr[c8g * 8 + 1][tid] << 16);
        pk.y = (u32)karr[c8g * 8 + 2][tid] | ((u32)karr[c8g * 8 + 3][tid] << 16);
        pk.z = (u32)karr[c8g * 8 + 4][tid] | ((u32)karr[c8g * 8 + 5][tid] << 16);
        pk.w = (u32)karr[c8g * 8 + 6][tid] | ((u32)karr[c8g * 8 + 7][tid] << 16);
        *(uint4*)(k2dq + ((b2 * 16 + grp * 4 + c8g) * 4096 + px0 + tid) * 4) = pk;
    }
}

// ---- kCB: fused kB+kC. Stage A: x A-frags feed v (8 nt) AND e-part1 (4 nt);
//           stage B: k2d A-frags -> e-part2; stage2: wd via MFMA; GN partials ----
__global__ __launch_bounds__(256, 2) void kCB_wd(
    const u32* __restrict__ xq, const u32* __restrict__ k2dq,
    const u32* __restrict__ wB, const u32* __restrict__ wB1,
    const float* __restrict__ vg, const float* __restrict__ vb,
    const float* __restrict__ vm, const float* __restrict__ vv,
    const float* __restrict__ eg, const float* __restrict__ eb,
    const float* __restrict__ em, const float* __restrict__ ev,
    const u32* __restrict__ wB2, const float* __restrict__ be2,
    u16* __restrict__ vh, u16* __restrict__ wdh,
    float* __restrict__ gnsum, float* __restrict__ gnsq)
{
    int tid  = threadIdx.x;
    int lane = tid & 63;
    int q    = __builtin_amdgcn_readfirstlane(tid >> 6);   // 0..3
    int tile = blockIdx.x & 31;
    int b2   = blockIdx.x >> 5;
    int px0  = tile * 128;
    int lrow = lane & 15;
    int lk   = lane >> 4;

    const uint4* wB4  = (const uint4*)wB;
    const uint4* wB14 = (const uint4*)wB1;

    f32x4 acc[2][4];    // e accumulator
    f32x4 accv[2][8];   // v accumulator
    #pragma unroll
    for (int mt = 0; mt < 2; ++mt) {
        #pragma unroll
        for (int nt = 0; nt < 4; ++nt) acc[mt][nt] = (f32x4){0.f, 0.f, 0.f, 0.f};
        #pragma unroll
        for (int nt = 0; nt < 8; ++nt) accv[mt][nt] = (f32x4){0.f, 0.f, 0.f, 0.f};
    }

    int pxA0 = px0 + (2 * q) * 16 + lrow;
    int pxA1 = pxA0 + 16;

    // Stage A: x quads -> v (wB1, 8 nt) + e-part1 (wB, 4 nt)
    #pragma unroll
    for (int kblk = 0; kblk < 4; ++kblk) {
        const u32* src = xq + ((b2 * 16 + kblk * 4 + lk) * 4096) * 4;
        ABcast a0, a1;
        a0.u = *(const uint4*)(src + pxA0 * 4);
        a1.u = *(const uint4*)(src + pxA1 * 4);
        #pragma unroll
        for (int nt = 0; nt < 8; ++nt) {
            ABcast bfr;
            bfr.u = wB14[(kblk * 8 + nt) * 64 + lane];
            accv[0][nt] = __builtin_amdgcn_mfma_f32_16x16x32_bf16(a0.v, bfr.v, accv[0][nt], 0, 0, 0);
            accv[1][nt] = __builtin_amdgcn_mfma_f32_16x16x32_bf16(a1.v, bfr.v, accv[1][nt], 0, 0, 0);
        }
        #pragma unroll
        for (int nt = 0; nt < 4; ++nt) {
            ABcast bfr;
            bfr.u = wB4[(kblk * 4 + nt) * 64 + lane];
            acc[0][nt] = __builtin_amdgcn_mfma_f32_16x16x32_bf16(a0.v, bfr.v, acc[0][nt], 0, 0, 0);
            acc[1][nt] = __builtin_amdgcn_mfma_f32_16x16x32_bf16(a1.v, bfr.v, acc[1][nt], 0, 0, 0);
        }
    }

    // v epilogue (kB's verified path)
    #pragma unroll
    for (int nt = 0; nt < 8; ++nt) {
        int ch = nt * 16 + lrow;
        float s = vg[ch] * rsqrtf(vv[ch] + EPSV);
        float t = vb[ch] - vm[ch] * s;
        #pragma unroll
        for (int mt = 0; mt < 2; ++mt) {
            float r0 = fmaf(accv[mt][nt].x, s, t);
            float r1 = fmaf(accv[mt][nt].y, s, t);
            float r2 = fmaf(accv[mt][nt].z, s, t);
            float r3 = fmaf(accv[mt][nt].w, s, t);
            uint2 pk;
            pk.x = bfbits(r0) | (bfbits(r1) << 16);
            pk.y = bfbits(r2) | (bfbits(r3) << 16);
            *(uint2*)(vh + (b2 * 128 + ch) * 4096 +
                      px0 + (2 * q + mt) * 16 + lk * 4) = pk;
        }
    }

    // Stage B: k2d quads -> e-part2
    #pragma unroll
    for (int kblk = 4; kblk < 8; ++kblk) {
        const u32* src = k2dq + ((b2 * 16 + (kblk & 3) * 4 + lk) * 4096) * 4;
        ABcast a0, a1;
        a0.u = *(const uint4*)(src + pxA0 * 4);
        a1.u = *(const uint4*)(src + pxA1 * 4);
        #pragma unroll
        for (int nt = 0; nt < 4; ++nt) {
            ABcast bfr;
            bfr.u = wB4[(kblk * 4 + nt) * 64 + lane];
            acc[0][nt] = __builtin_amdgcn_mfma_f32_16x16x32_bf16(a0.v, bfr.v, acc[0][nt], 0, 0, 0);
            acc[1][nt] = __builtin_amdgcn_mfma_f32_16x16x32_bf16(a1.v, bfr.v, acc[1][nt], 0, 0, 0);
        }
    }

    // e epilogue: BN+ReLU, pack channel pairs, write e_s2[c2][px]
    __shared__ __align__(16) u32 e_s2[32][132];
    #pragma unroll
    for (int nt = 0; nt < 4; ++nt) {
        int ch = nt * 16 + lrow;
        float s = eg[ch] * rsqrtf(ev[ch] + EPSV);
        float t = eb[ch] - em[ch] * s;
        #pragma unroll
        for (int mt = 0; mt < 2; ++mt) {
            float r0 = fmaxf(fmaf(acc[mt][nt].x, s, t), 0.f);
            float r1 = fmaxf(fmaf(acc[mt][nt].y, s, t), 0.f);
            float r2 = fmaxf(fmaf(acc[mt][nt].z, s, t), 0.f);
            float r3 = fmaxf(fmaf(acc[mt][nt].w, s, t), 0.f);
            float p0 = __shfl_xor(r0, 1, 64);
            float p1 = __shfl_xor(r1, 1, 64);
            float p2 = __shfl_xor(r2, 1, 64);
            float p3 = __shfl_xor(r3, 1, 64);
            if (!(lane & 1)) {
                uint4 pk;
                pk.x = bfbits(r0) | (bfbits(p0) << 16);
                pk.y = bfbits(r1) | (bfbits(p1) << 16);
                pk.z = bfbits(r2) | (bfbits(p2) << 16);
                pk.w = bfbits(r3) | (bfbits(p3) << 16);
                *(uint4*)&e_s2[nt * 8 + (lrow >> 1)][(2 * q + mt) * 16 + lk * 4] = pk;
            }
        }
    }
    __syncthreads();

    // stage2: wd = e @ we2^T + bias via MFMA
    const uint4* wB24 = (const uint4*)wB2;
    f32x4 acc2[2][6];
    #pragma unroll
    for (int mt = 0; mt < 2; ++mt)
        #pragma unroll
        for (int nt = 0; nt < 6; ++nt)
            acc2[mt][nt] = (f32x4){0.f, 0.f, 0.f, 0.f};

    #pragma unroll
    for (int kb2 = 0; kb2 < 2; ++kb2) {
        int c2r = kb2 * 16 + lk * 4;
        ABcast a0, a1;
        int pl0 = (2 * q) * 16 + lrow;
        int pl1 = pl0 + 16;
        a0.u.x = e_s2[c2r + 0][pl0];
        a0.u.y = e_s2[c2r + 1][pl0];
        a0.u.z = e_s2[c2r + 2][pl0];
        a0.u.w = e_s2[c2r + 3][pl0];
        a1.u.x = e_s2[c2r + 0][pl1];
        a1.u.y = e_s2[c2r + 1][pl1];
        a1.u.z = e_s2[c2r + 2][pl1];
        a1.u.w = e_s2[c2r + 3][pl1];
        #pragma unroll
        for (int nt = 0; nt < 6; ++nt) {
            ABcast bfr;
            bfr.u = wB24[(kb2 * 6 + nt) * 64 + lane];
            acc2[0][nt] = __builtin_amdgcn_mfma_f32_16x16x32_bf16(a0.v, bfr.v, acc2[0][nt], 0, 0, 0);
            acc2[1][nt] = __builtin_amdgcn_mfma_f32_16x16x32_bf16(a1.v, bfr.v, acc2[1][nt], 0, 0, 0);
        }
    }

    __shared__ float s_sum[96][4], s_sq[96][4];
    #pragma unroll
    for (int nt = 0; nt < 6; ++nt) {
        int ch = nt * 16 + lrow;
        float bias = be2[ch];
        float lsum = 0.f, lsq = 0.f;
        #pragma unroll
        for (int mt = 0; mt < 2; ++mt) {
            float v0 = acc2[mt][nt].x + bias;
            float v1 = acc2[mt][nt].y + bias;
            float v2 = acc2[mt][nt].z + bias;
            float v3 = acc2[mt][nt].w + bias;
            uint2 pk;
            pk.x = bfbits(v0) | (bfbits(v1) << 16);
            pk.y = bfbits(v2) | (bfbits(v3) << 16);
            *(uint2*)(wdh + (b2 * 96 + ch) * 4096 +
                      px0 + (2 * q + mt) * 16 + lk * 4) = pk;
            lsum += v0 + v1 + v2 + v3;
            lsq  += v0 * v0 + v1 * v1 + v2 * v2 + v3 * v3;
        }
        lsum += __shfl_xor(lsum, 16, 64);
        lsum += __shfl_xor(lsum, 32, 64);
        lsq  += __shfl_xor(lsq, 16, 64);
        lsq  += __shfl_xor(lsq, 32, 64);
        if (lane < 16) { s_sum[ch][q] = lsum; s_sq[ch][q] = lsq; }
    }
    __syncthreads();
    if (tid < 32) {
        float ss = 0.f, sq = 0.f;
        #pragma unroll
        for (int j = 0; j < 3; ++j) {
            int ch = tid * 3 + j;
            ss += s_sum[ch][0] + s_sum[ch][1] + s_sum[ch][2] + s_sum[ch][3];
            sq += s_sq[ch][0] + s_sq[ch][1] + s_sq[ch][2] + s_sq[ch][3];
        }
        atomicAdd(&gnsum[b2 * 32 + tid], ss);
        atomicAdd(&gnsq [b2 * 32 + tid], sq);
    }
}

// ---- kD: agg = SiLU(BN2(sum_k GN(wd)*unfold(v))) -> bf16 aggh, + gap ----
__global__ __launch_bounds__(256, 8) void kD_agg(
    const u16* __restrict__ wdh, const u16* __restrict__ vh,
    const float* __restrict__ gnsum, const float* __restrict__ gnsq,
    const float* __restrict__ gng, const float* __restrict__ gnb,
    const float* __restrict__ g, const float* __restrict__ bb,
    const float* __restrict__ m, const float* __restrict__ vr,
    u16* __restrict__ aggh, float* __restrict__ gap)
{
    int blk   = blockIdx.x;
    int strip = blk & 7;
    int c1    = (blk >> 3) & 31;
    int bi    = blk >> 8;
    int px0   = strip * 512 + threadIdx.x * 2;
    const float inv = 1.f / 12288.f;

    float sch[4], tch[4], gl[4];
    #pragma unroll
    for (int ch = 0; ch < 4; ++ch) {
        int c = c1 * 4 + ch;
        float s = g[c] * rsqrtf(vr[c] + EPSV);
        sch[ch] = s; tch[ch] = bb[c] - m[c] * s; gl[ch] = 0.f;
    }
    float gg[3], gb[3];
    #pragma unroll
    for (int k = 0; k < 3; ++k) { gg[k] = gng[c1 * 3 + k]; gb[k] = gnb[c1 * 3 + k]; }

    float2 vreg[4][3];
    #pragma unroll
    for (int ch = 0; ch < 4; ++ch) {
        vreg[ch][0] = make_float2(0.f, 0.f);
        u32 v1u = *(const u32*)(vh + ((bi * 8 + 0) * 128 + c1 * 4 + ch) * 4096 + px0);
        u32 v2u = *(const u32*)(vh + ((bi * 8 + 1) * 128 + c1 * 4 + ch) * 4096 + px0);
        vreg[ch][1] = make_float2(bflo(v1u), bfhi(v1u));
        vreg[ch][2] = make_float2(bflo(v2u), bfhi(v2u));
    }

    for (int ni = 0; ni < 8; ++ni) {
        int b2 = bi * 8 + ni;
        float mu = gnsum[b2 * 32 + c1] * inv;
        float var = fmaf(gnsq[b2 * 32 + c1], inv, -mu * mu);
        float rs = rsqrtf(fmaxf(var, 0.f) + EPSV);
        float2 wn[3];
        #pragma unroll
        for (int k = 0; k < 3; ++k) {
            int nf = ni + k - 1;
            if (nf >= 0 && nf < 8) {
                u32 wvu = *(const u32*)(wdh + ((b2 * 96 + c1 * 3 + k) * 4096 + px0));
                wn[k].x = fmaf((bflo(wvu) - mu) * rs, gg[k], gb[k]);
                wn[k].y = fmaf((bfhi(wvu) - mu) * rs, gg[k], gb[k]);
            } else {
                wn[k] = make_float2(0.f, 0.f);
            }
        }
        #pragma unroll
        for (int ch = 0; ch < 4; ++ch) {
            float a0 = 0.f, a1 = 0.f;
            #pragma unroll
            for (int k = 0; k < 3; ++k) {
                a0 = fmaf(wn[k].x, vreg[ch][k].x, a0);
                a1 = fmaf(wn[k].y, vreg[ch][k].y, a1);
            }
            float y0 = fmaf(a0, sch[ch], tch[ch]);
            float y1 = fmaf(a1, sch[ch], tch[ch]);
            float r0 = y0 / (1.f + __expf(-y0));
            float r1 = y1 / (1.f + __expf(-y1));
            *(u32*)(aggh + (b2 * 128 + c1 * 4 + ch) * 4096 + px0) =
                bfbits(r0) | (bfbits(r1) << 16);
            gl[ch] += r0 + r1;
        }
        if (ni < 7) {
            #pragma unroll
            for (int ch = 0; ch < 4; ++ch) {
                vreg[ch][0] = vreg[ch][1];
                vreg[ch][1] = vreg[ch][2];
                if (ni + 2 < 8) {
                    u32 vu = *(const u32*)(vh + ((bi * 8 + ni + 2) * 128 + c1 * 4 + ch) * 4096 + px0);
                    vreg[ch][2] = make_float2(bflo(vu), bfhi(vu));
                }
            }
        }
    }

    __shared__ float sm[4][4];
    int lane = threadIdx.x & 63, wid = threadIdx.x >> 6;
    #pragma unroll
    for (int ch = 0; ch < 4; ++ch) {
        float s = gl[ch];
        #pragma unroll
        for (int off = 32; off; off >>= 1) s += __shfl_down(s, off, 64);
        if (lane == 0) sm[ch][wid] = s;
    }
    __syncthreads();
    if (threadIdx.x < 4) {
        float* sr = sm[threadIdx.x];
        atomicAdd(&gap[bi * 128 + c1 * 4 + threadIdx.x], sr[0] + sr[1] + sr[2] + sr[3]);
    }
}

// ---- kE: SE head, merged (grid 4 = bi, 128 threads) ----
__global__ __launch_bounds__(128) void kE_attn(
    const float* __restrict__ gap,
    const float* __restrict__ w1, const float* __restrict__ b1,
    const float* __restrict__ g, const float* __restrict__ bb,
    const float* __restrict__ m, const float* __restrict__ vr,
    const float* __restrict__ w2, const float* __restrict__ b2v,
    float* __restrict__ attn)
{
    __shared__ float a_s[128];
    int bi = blockIdx.x;
    int oc = threadIdx.x;
    float acc = b1[oc];
    const float* gp = gap + bi * 128;
    const float* wp = w1 + oc * 128;
    for (int c = 0; c < 128; c += 4) {
        const float4 w4 = *(const float4*)(wp + c);
        acc = fmaf(gp[c + 0] * (1.f / 32768.f), w4.x, acc);
        acc = fmaf(gp[c + 1] * (1.f / 32768.f), w4.y, acc);
        acc = fmaf(gp[c + 2] * (1.f / 32768.f), w4.z, acc);
        acc = fmaf(gp[c + 3] * (1.f / 32768.f), w4.w, acc);
    }
    float s = g[oc] * rsqrtf(vr[oc] + EPSV);
    a_s[oc] = fmaxf(fmaf(acc, s, bb[oc] - m[oc] * s), 0.f);
    __syncthreads();

    int cc = threadIdx.x;
    float l0 = b2v[cc * 2], l1 = b2v[cc * 2 + 1];
    const float* w0p = w2 + (cc * 2) * 128;
    const float* w1p = w2 + (cc * 2 + 1) * 128;
    for (int j = 0; j < 128; j += 4) {
        const float4 wa4 = *(const float4*)(w0p + j);
        const float4 wb4 = *(const float4*)(w1p + j);
        l0 = fmaf(a_s[j + 0], wa4.x, l0); l1 = fmaf(a_s[j + 0], wb4.x, l1);
        l0 = fmaf(a_s[j + 1], wa4.y, l0); l1 = fmaf(a_s[j + 1], wb4.y, l1);
        l0 = fmaf(a_s[j + 2], wa4.z, l0); l1 = fmaf(a_s[j + 2], wb4.z, l1);
        l0 = fmaf(a_s[j + 3], wa4.w, l0); l1 = fmaf(a_s[j + 3], wb4.w, l1);
    }
    float mx = fmaxf(l0, l1);
    float e0 = __expf(l0 - mx), e1 = __expf(l1 - mx);
    float inv = 1.f / (e0 + e1);
    attn[bi * 256 + cc * 2]     = e0 * inv;
    attn[bi * 256 + cc * 2 + 1] = e1 * inv;
}

// ---- kF: out = attn0*agg + attn1*k2d; block = (b2, c8, strip); thread = 4 px ----
__global__ __launch_bounds__(256, 8) void kF_out(
    float* __restrict__ out, const u16* __restrict__ aggh,
    const u32* __restrict__ k2dq, const float* __restrict__ attn)
{
    int blk   = blockIdx.x;
    int strip = blk & 3;
    int c8    = (blk >> 2) & 15;
    int b2    = blk >> 6;
    int bi    = b2 >> 3;
    int p     = strip * 1024 + threadIdx.x * 4;

    const u32* kp = k2dq + ((b2 * 16 + c8) * 4096 + p) * 4;
    uint4 kq[4];
    #pragma unroll
    for (int i = 0; i < 4; ++i) kq[i] = *(const uint4*)(kp + i * 4);

    #pragma unroll
    for (int j = 0; j < 8; ++j) {
        int ch = c8 * 8 + j;
        float a0 = attn[bi * 256 + ch * 2];
        float a1 = attn[bi * 256 + ch * 2 + 1];
        uint2 ag = *(const uint2*)(aggh + (b2 * 128 + ch) * 4096 + p);
        float av[4] = { bflo(ag.x), bfhi(ag.x), bflo(ag.y), bfhi(ag.y) };
        float4 r;
        u32 kd0 = (&kq[0].x)[j >> 1];
        u32 kd1 = (&kq[1].x)[j >> 1];
        u32 kd2 = (&kq[2].x)[j >> 1];
        u32 kd3 = (&kq[3].x)[j >> 1];
        float kv0 = (j & 1) ? bfhi(kd0) : bflo(kd0);
        float kv1 = (j & 1) ? bfhi(kd1) : bflo(kd1);
        float kv2 = (j & 1) ? bfhi(kd2) : bflo(kd2);
        float kv3 = (j & 1) ? bfhi(kd3) : bflo(kd3);
        r.x = fmaf(a0, av[0], a1 * kv0);
        r.y = fmaf(a0, av[1], a1 * kv1);
        r.z = fmaf(a0, av[2], a1 * kv2);
        r.w = fmaf(a0, av[3], a1 * kv3);
        *(float4*)(out + (b2 * 128 + ch) * 4096 + p) = r;
    }
}

extern "C" void kernel_launch(void* const* d_in, const int* in_sizes, int n_in,
                              void* d_out, int out_size, void* d_ws, size_t ws_size,
                              hipStream_t stream)
{
    const float* x      = (const float*)d_in[0];
    const float* w_key  = (const float*)d_in[1];
    const float* bnk_g  = (const float*)d_in[2];
    const float* bnk_b  = (const float*)d_in[3];
    const float* bnk_m  = (const float*)d_in[4];
    const float* bnk_v  = (const float*)d_in[5];
    const float* w_e1   = (const float*)d_in[6];
    const float* bne_g  = (const float*)d_in[7];
    const float* bne_b  = (const float*)d_in[8];
    const float* bne_m  = (const float*)d_in[9];
    const float* bne_v  = (const float*)d_in[10];
    const float* w_e2   = (const float*)d_in[11];
    const float* b_e2   = (const float*)d_in[12];
    const float* gn_g   = (const float*)d_in[13];
    const float* gn_b   = (const float*)d_in[14];
    const float* w_1x1  = (const float*)d_in[15];
    const float* bn1_g  = (const float*)d_in[16];
    const float* bn1_b  = (const float*)d_in[17];
    const float* bn1_m  = (const float*)d_in[18];
    const float* bn1_v  = (const float*)d_in[19];
    const float* bn2_g  = (const float*)d_in[20];
    const float* bn2_b  = (const float*)d_in[21];
    const float* bn2_m  = (const float*)d_in[22];
    const float* bn2_v  = (const float*)d_in[23];
    const float* w_se1  = (const float*)d_in[24];
    const float* b_se1  = (const float*)d_in[25];
    const float* bnse_g = (const float*)d_in[26];
    const float* bnse_b = (const float*)d_in[27];
    const float* bnse_m = (const float*)d_in[28];
    const float* bnse_v = (const float*)d_in[29];
    const float* w_se2  = (const float*)d_in[30];
    const float* b_se2  = (const float*)d_in[31];

    float* ws    = (float*)d_ws;
    u32*  xq    = (u32*)ws;
    u32*  k2dq  = (u32*)(ws + 8388608);
    u16*  vh    = (u16*)(ws + 16777216);
    u16*  aggh  = (u16*)(ws + 25165824);
    u16*  wdh   = (u16*)(ws + 33554432);
    u32*  wkF   = (u32*)(ws + 39845888);
    u32*  wB1   = wkF + 6144;
    u32*  wB    = wB1 + 8192;
    u32*  wB2   = wB + 8192;
    float* st   = ws + 46137344;
    float* gnsum  = st;
    float* gnsq   = st + 1024;
    float* gap    = st + 2048;
    float* attn   = st + 4608;

    kXW_cvt<<<8192, 256, 0, stream>>>(x, xq, w_key, w_1x1, w_e1, w_e2,
                                      wkF, wB1, wB, wB2, gnsum);
    kA_key<<<2048, 256, 0, stream>>>(xq, wkF, bnk_g, bnk_b, bnk_m, bnk_v, k2dq, gap);
    kCB_wd<<<1024, 256, 0, stream>>>(xq, k2dq, wB, wB1,
                                     bn1_g, bn1_b, bn1_m, bn1_v,
                                     bne_g, bne_b, bne_m, bne_v,
                                     wB2, b_e2, vh, wdh, gnsum, gnsq);
    kD_agg<<<1024, 256, 0, stream>>>(wdh, vh, gnsum, gnsq, gn_g, gn_b,
                                     bn2_g, bn2_b, bn2_m, bn2_v, aggh, gap);
    kE_attn<<<4, 128, 0, stream>>>(gap, w_se1, b_se1, bnse_g, bnse_b, bnse_m, bnse_v,
                                   w_se2, b_se2, attn);
    kF_out<<<2048, 256, 0, stream>>>((float*)d_out, aggh, k2dq, attn);
}

// Round 20
// 135.876 us; speedup vs baseline: 1.0663x; 1.0663x over previous
//
#include <hip/hip_runtime.h>

#define EPSV 1e-5f
typedef unsigned short u16;
typedef unsigned int u32;

// Problem constants: B=4, N=8, B2=32, C=128, H=W=64, HW=4096, KS=3
// Workspace (float offsets):
//   [0,        8388608)  xq    (u32 quad-interleaved bf16 x: [b2][c8][px][4dw])
//   [8388608, 16777216)  k2dq  (u32 quad-interleaved bf16 k2d, same layout as xq)
//   [16777216,25165824)  vh    (u16 bf16, standard layout)
//   [25165824,33554432)  aggh  (u16 bf16, standard layout)
//   [33554432,39845888)  wdh   (u16 bf16, standard layout)
//   [39845888,39871488)  packed weights: wkF[6144] wB1[8192] wB[8192] wB2[3072]
//   stats @46137344: gnsum[1024] gnsq[1024] gap[512] ... attn @ +4608
typedef __attribute__((ext_vector_type(8))) __bf16 bf16x8;
typedef __attribute__((ext_vector_type(4))) float f32x4;
union ABcast { uint4 u; bf16x8 v; };

__device__ __forceinline__ u32 bfbits(float f) {   // RNE f32->bf16 bits
    u32 u = __float_as_uint(f);
    u += 0x7fff + ((u >> 16) & 1);
    return u >> 16;
}
__device__ __forceinline__ float bflo(u32 p) { return __uint_as_float(p << 16); }
__device__ __forceinline__ float bfhi(u32 p) { return __uint_as_float(p & 0xffff0000u); }

// ---- kXW: x -> xq (quad bf16), + weight packing (blocks 0..99), + stats zero ----
__global__ __launch_bounds__(256, 8) void kXW_cvt(
    const float* __restrict__ x, u32* __restrict__ xq,
    const float* __restrict__ wk, const float* __restrict__ w1,
    const float* __restrict__ we1, const float* __restrict__ we2,
    u32* __restrict__ wkF, u32* __restrict__ wB1,
    u32* __restrict__ wB, u32* __restrict__ wB2,
    float* __restrict__ stats_zero)
{
    int qid = blockIdx.x * 256 + threadIdx.x;   // 2,097,152 total (32*16*4096)
    int px  = qid & 4095;
    int c8g = qid >> 12;                        // b2*16 + c8
    const float* xp = x + (c8g * 8) * 4096 + px;
    uint4 o;
    o.x = bfbits(xp[0])        | (bfbits(xp[4096])     << 16);
    o.y = bfbits(xp[2 * 4096]) | (bfbits(xp[3 * 4096]) << 16);
    o.z = bfbits(xp[4 * 4096]) | (bfbits(xp[5 * 4096]) << 16);
    o.w = bfbits(xp[6 * 4096]) | (bfbits(xp[7 * 4096]) << 16);
    *(uint4*)(xq + (c8g * 4096 + px) * 4) = o;

    int i = qid;                                // weight packing: blocks 0..99
    if (i < 2560) stats_zero[i] = 0.f;          // gnsum, gnsq, gap
    if (i < 6144) {                             // wkF: B-frags of w_key per (grp,dk)
        int jj = i & 3;
        int ln = (i >> 2) & 63;
        int nt = (i >> 8) & 1;
        int rest = i >> 9;
        int grp = rest / 3, dk = rest % 3;
        int n = nt * 16 + (ln & 15);
        int k = (ln >> 4) * 8 + 2 * jj;
        int oo = grp * 32 + n;
        wkF[i] = bfbits(wk[oo * 96 + k * 3 + dk]) |
                 (bfbits(wk[oo * 96 + (k + 1) * 3 + dk]) << 16);
    } else if (i < 14336) {                     // wB1: B-frags of w_1x1
        int j2 = i - 6144;
        int jj = j2 & 3;
        int ln = (j2 >> 2) & 63;
        int nt = (j2 >> 8) & 7;
        int kb = j2 >> 11;
        int n = nt * 16 + (ln & 15);
        int k = kb * 32 + (ln >> 4) * 8 + 2 * jj;
        wB1[j2] = bfbits(w1[n * 128 + k]) | (bfbits(w1[n * 128 + k + 1]) << 16);
    } else if (i < 22528) {                     // wB: B-frags of w_e1
        int j2 = i - 14336;
        int jj = j2 & 3;
        int ln = (j2 >> 2) & 63;
        int nt = (j2 >> 8) & 3;
        int kb = j2 >> 10;
        int n  = nt * 16 + (ln & 15);
        int k  = kb * 32 + (ln >> 4) * 8 + 2 * jj;
        wB[j2] = bfbits(we1[n * 256 + k]) | (bfbits(we1[n * 256 + k + 1]) << 16);
    } else if (i < 25600) {                     // wB2: B-frags of w_e2 (96x64)
        int j2 = i - 22528;
        int jj = j2 & 3;
        int ln = (j2 >> 2) & 63;
        int rest = j2 >> 8;
        int kb = rest / 6, nt = rest % 6;
        int n = nt * 16 + (ln & 15);
        int k = kb * 32 + (ln >> 4) * 8 + 2 * jj;
        wB2[j2] = bfbits(we2[n * 64 + k]) | (bfbits(we2[n * 64 + k + 1]) << 16);
    }
}

// ---- kA: key_embed via MFMA -> k2dq (quad layout via LDS repack), + gap ----
__global__ __launch_bounds__(256, 4) void kA_key(
    const u32* __restrict__ xq, const u32* __restrict__ wkF,
    const float* __restrict__ g, const float* __restrict__ bb,
    const float* __restrict__ m, const float* __restrict__ vr,
    u32* __restrict__ k2dq, float* __restrict__ gap)
{
    int tid  = threadIdx.x;
    int lane = tid & 63;
    int q    = __builtin_amdgcn_readfirstlane(tid >> 6);   // 0..3
    int blk  = blockIdx.x;
    int tile = blk & 15;
    int grp  = (blk >> 4) & 3;
    int b2   = blk >> 6;
    int px0  = tile * 256;
    int bi = b2 >> 3, ni = b2 & 7;
    int lrow = lane & 15, lk = lane >> 4;
    const uint4* wkF4 = (const uint4*)wkF;

    f32x4 acc[4][2];
    #pragma unroll
    for (int mt = 0; mt < 4; ++mt)
        #pragma unroll
        for (int nt = 0; nt < 2; ++nt)
            acc[mt][nt] = (f32x4){0.f, 0.f, 0.f, 0.f};

    int pxA[4];
    #pragma unroll
    for (int mt = 0; mt < 4; ++mt) pxA[mt] = px0 + (4 * q + mt) * 16 + lrow;

    #pragma unroll
    for (int dk = 0; dk < 3; ++dk) {
        int nf = ni + dk - 1;
        if (nf >= 0 && nf < 8) {
            const u32* src = xq + (((bi * 8 + nf) * 16 + grp * 4 + lk) * 4096) * 4;
            ABcast a[4];
            #pragma unroll
            for (int mt = 0; mt < 4; ++mt)
                a[mt].u = *(const uint4*)(src + pxA[mt] * 4);
            #pragma unroll
            for (int nt = 0; nt < 2; ++nt) {
                ABcast bfr;
                bfr.u = wkF4[((grp * 3 + dk) * 2 + nt) * 64 + lane];
                #pragma unroll
                for (int mt = 0; mt < 4; ++mt)
                    acc[mt][nt] = __builtin_amdgcn_mfma_f32_16x16x32_bf16(
                        a[mt].v, bfr.v, acc[mt][nt], 0, 0, 0);
            }
        }
    }

    __shared__ u16  karr[32][260];   // ch-within-grp x px, padded
    __shared__ float ssum[32][4];
    #pragma unroll
    for (int nt = 0; nt < 2; ++nt) {
        int ch = grp * 32 + nt * 16 + lrow;
        float s = g[ch] * rsqrtf(vr[ch] + EPSV);
        float t = bb[ch] - m[ch] * s;
        float lsum = 0.f;
        #pragma unroll
        for (int mt = 0; mt < 4; ++mt) {
            float r0 = fmaxf(fmaf(acc[mt][nt].x, s, t), 0.f);
            float r1 = fmaxf(fmaf(acc[mt][nt].y, s, t), 0.f);
            float r2 = fmaxf(fmaf(acc[mt][nt].z, s, t), 0.f);
            float r3 = fmaxf(fmaf(acc[mt][nt].w, s, t), 0.f);
            lsum += r0 + r1 + r2 + r3;
            int pxl = (4 * q + mt) * 16 + lk * 4;
            u16* kr = &karr[nt * 16 + lrow][pxl];
            kr[0] = (u16)bfbits(r0);
            kr[1] = (u16)bfbits(r1);
            kr[2] = (u16)bfbits(r2);
            kr[3] = (u16)bfbits(r3);
        }
        lsum += __shfl_xor(lsum, 16, 64);
        lsum += __shfl_xor(lsum, 32, 64);
        if (lane < 16) ssum[nt * 16 + lrow][q] = lsum;
    }
    __syncthreads();
    if (tid < 32) {
        float* sr = ssum[tid];
        atomicAdd(&gap[bi * 128 + grp * 32 + tid], sr[0] + sr[1] + sr[2] + sr[3]);
    }
    // quad-pack: thread = 1 px, 4 c8 groups
    #pragma unroll
    for (int c8g = 0; c8g < 4; ++c8g) {
        uint4 pk;
        pk.x = (u32)karr[c8g * 8 + 0][tid] | ((u32)karr[c8g * 8 + 1][tid] << 16);
        pk.y = (u32)karr[c8g * 8 + 2][tid] | ((u32)karr[c8g * 8 + 3][tid] << 16);
        pk.z = (u32)karr[c8g * 8 + 4][tid] | ((u32)karr[c8g * 8 + 5][tid] << 16);
        pk.w = (u32)karr[c8g * 8 + 6][tid] | ((u32)karr[c8g * 8 + 7][tid] << 16);
        *(uint4*)(k2dq + ((b2 * 16 + grp * 4 + c8g) * 4096 + px0 + tid) * 4) = pk;
    }
}

// ---- kB: v = BN(x @ w_1x1) via MFMA -> bf16 vh (standard layout) ----
__global__ __launch_bounds__(256, 3) void kB_val(
    const u32* __restrict__ xq, const u32* __restrict__ wB1,
    const float* __restrict__ g, const float* __restrict__ bb,
    const float* __restrict__ m, const float* __restrict__ vr,
    u16* __restrict__ vh)
{
    int tid  = threadIdx.x;
    int lane = tid & 63;
    int q    = __builtin_amdgcn_readfirstlane(tid >> 6);   // 0..3
    int tile = blockIdx.x & 31;
    int b2   = blockIdx.x >> 5;
    int px0  = tile * 128;
    int lrow = lane & 15, lk = lane >> 4;

    const uint4* wB14 = (const uint4*)wB1;

    f32x4 acc[2][8];
    #pragma unroll
    for (int mt = 0; mt < 2; ++mt)
        #pragma unroll
        for (int nt = 0; nt < 8; ++nt)
            acc[mt][nt] = (f32x4){0.f, 0.f, 0.f, 0.f};

    int pxA0 = px0 + (2 * q) * 16 + lrow;
    int pxA1 = pxA0 + 16;

    #pragma unroll
    for (int kblk = 0; kblk < 4; ++kblk) {
        const u32* src = xq + ((b2 * 16 + kblk * 4 + lk) * 4096) * 4;
        ABcast a0, a1;
        a0.u = *(const uint4*)(src + pxA0 * 4);
        a1.u = *(const uint4*)(src + pxA1 * 4);
        #pragma unroll
        for (int nt = 0; nt < 8; ++nt) {
            ABcast bfr;
            bfr.u = wB14[(kblk * 8 + nt) * 64 + lane];
            acc[0][nt] = __builtin_amdgcn_mfma_f32_16x16x32_bf16(a0.v, bfr.v, acc[0][nt], 0, 0, 0);
            acc[1][nt] = __builtin_amdgcn_mfma_f32_16x16x32_bf16(a1.v, bfr.v, acc[1][nt], 0, 0, 0);
        }
    }

    #pragma unroll
    for (int nt = 0; nt < 8; ++nt) {
        int ch = nt * 16 + lrow;
        float s = g[ch] * rsqrtf(vr[ch] + EPSV);
        float t = bb[ch] - m[ch] * s;
        #pragma unroll
        for (int mt = 0; mt < 2; ++mt) {
            float r0 = fmaf(acc[mt][nt].x, s, t);
            float r1 = fmaf(acc[mt][nt].y, s, t);
            float r2 = fmaf(acc[mt][nt].z, s, t);
            float r3 = fmaf(acc[mt][nt].w, s, t);
            uint2 pk;
            pk.x = bfbits(r0) | (bfbits(r1) << 16);
            pk.y = bfbits(r2) | (bfbits(r3) << 16);
            *(uint2*)(vh + (b2 * 128 + ch) * 4096 +
                      px0 + (2 * q + mt) * 16 + lk * 4) = pk;
        }
    }
}

// ---- kC: stage1 e via MFMA (x and k2d both quad); stage2 wd via MFMA; GN partials ----
__global__ __launch_bounds__(256, 3) void kC_wd(
    const u32* __restrict__ xq, const u32* __restrict__ k2dq,
    const u32* __restrict__ wB,
    const float* __restrict__ eg, const float* __restrict__ eb,
    const float* __restrict__ em, const float* __restrict__ ev,
    const u32* __restrict__ wB2, const float* __restrict__ be2,
    u16* __restrict__ wdh, float* __restrict__ gnsum, float* __restrict__ gnsq)
{
    int tid  = threadIdx.x;
    int lane = tid & 63;
    int q    = __builtin_amdgcn_readfirstlane(tid >> 6);   // 0..3
    int tile = blockIdx.x & 31;
    int b2   = blockIdx.x >> 5;
    int px0  = tile * 128;
    int lrow = lane & 15;
    int lk   = lane >> 4;

    const uint4* wB4 = (const uint4*)wB;

    f32x4 acc[2][4];
    #pragma unroll
    for (int mt = 0; mt < 2; ++mt)
        #pragma unroll
        for (int nt = 0; nt < 4; ++nt)
            acc[mt][nt] = (f32x4){0.f, 0.f, 0.f, 0.f};

    int pxA0 = px0 + (2 * q) * 16 + lrow;
    int pxA1 = pxA0 + 16;

    #pragma unroll
    for (int kblk = 0; kblk < 8; ++kblk) {
        const u32* base = (kblk < 4) ? xq : k2dq;
        const u32* src = base + ((b2 * 16 + (kblk & 3) * 4 + lk) * 4096) * 4;
        ABcast a0, a1;
        a0.u = *(const uint4*)(src + pxA0 * 4);
        a1.u = *(const uint4*)(src + pxA1 * 4);
        #pragma unroll
        for (int nt = 0; nt < 4; ++nt) {
            ABcast bfr;
            bfr.u = wB4[(kblk * 4 + nt) * 64 + lane];
            acc[0][nt] = __builtin_amdgcn_mfma_f32_16x16x32_bf16(a0.v, bfr.v, acc[0][nt], 0, 0, 0);
            acc[1][nt] = __builtin_amdgcn_mfma_f32_16x16x32_bf16(a1.v, bfr.v, acc[1][nt], 0, 0, 0);
        }
    }

    __shared__ __align__(16) u32 e_s2[32][132];
    #pragma unroll
    for (int nt = 0; nt < 4; ++nt) {
        int ch = nt * 16 + lrow;
        float s = eg[ch] * rsqrtf(ev[ch] + EPSV);
        float t = eb[ch] - em[ch] * s;
        #pragma unroll
        for (int mt = 0; mt < 2; ++mt) {
            float r0 = fmaxf(fmaf(acc[mt][nt].x, s, t), 0.f);
            float r1 = fmaxf(fmaf(acc[mt][nt].y, s, t), 0.f);
            float r2 = fmaxf(fmaf(acc[mt][nt].z, s, t), 0.f);
            float r3 = fmaxf(fmaf(acc[mt][nt].w, s, t), 0.f);
            float p0 = __shfl_xor(r0, 1, 64);
            float p1 = __shfl_xor(r1, 1, 64);
            float p2 = __shfl_xor(r2, 1, 64);
            float p3 = __shfl_xor(r3, 1, 64);
            if (!(lane & 1)) {
                uint4 pk;
                pk.x = bfbits(r0) | (bfbits(p0) << 16);
                pk.y = bfbits(r1) | (bfbits(p1) << 16);
                pk.z = bfbits(r2) | (bfbits(p2) << 16);
                pk.w = bfbits(r3) | (bfbits(p3) << 16);
                *(uint4*)&e_s2[nt * 8 + (lrow >> 1)][(2 * q + mt) * 16 + lk * 4] = pk;
            }
        }
    }
    __syncthreads();

    const uint4* wB24 = (const uint4*)wB2;
    f32x4 acc2[2][6];
    #pragma unroll
    for (int mt = 0; mt < 2; ++mt)
        #pragma unroll
        for (int nt = 0; nt < 6; ++nt)
            acc2[mt][nt] = (f32x4){0.f, 0.f, 0.f, 0.f};

    #pragma unroll
    for (int kb2 = 0; kb2 < 2; ++kb2) {
        int c2r = kb2 * 16 + lk * 4;
        ABcast a0, a1;
        int pl0 = (2 * q) * 16 + lrow;
        int pl1 = pl0 + 16;
        a0.u.x = e_s2[c2r + 0][pl0];
        a0.u.y = e_s2[c2r + 1][pl0];
        a0.u.z = e_s2[c2r + 2][pl0];
        a0.u.w = e_s2[c2r + 3][pl0];
        a1.u.x = e_s2[c2r + 0][pl1];
        a1.u.y = e_s2[c2r + 1][pl1];
        a1.u.z = e_s2[c2r + 2][pl1];
        a1.u.w = e_s2[c2r + 3][pl1];
        #pragma unroll
        for (int nt = 0; nt < 6; ++nt) {
            ABcast bfr;
            bfr.u = wB24[(kb2 * 6 + nt) * 64 + lane];
            acc2[0][nt] = __builtin_amdgcn_mfma_f32_16x16x32_bf16(a0.v, bfr.v, acc2[0][nt], 0, 0, 0);
            acc2[1][nt] = __builtin_amdgcn_mfma_f32_16x16x32_bf16(a1.v, bfr.v, acc2[1][nt], 0, 0, 0);
        }
    }

    __shared__ float s_sum[96][4], s_sq[96][4];
    #pragma unroll
    for (int nt = 0; nt < 6; ++nt) {
        int ch = nt * 16 + lrow;
        float bias = be2[ch];
        float lsum = 0.f, lsq = 0.f;
        #pragma unroll
        for (int mt = 0; mt < 2; ++mt) {
            float v0 = acc2[mt][nt].x + bias;
            float v1 = acc2[mt][nt].y + bias;
            float v2 = acc2[mt][nt].z + bias;
            float v3 = acc2[mt][nt].w + bias;
            uint2 pk;
            pk.x = bfbits(v0) | (bfbits(v1) << 16);
            pk.y = bfbits(v2) | (bfbits(v3) << 16);
            *(uint2*)(wdh + (b2 * 96 + ch) * 4096 +
                      px0 + (2 * q + mt) * 16 + lk * 4) = pk;
            lsum += v0 + v1 + v2 + v3;
            lsq  += v0 * v0 + v1 * v1 + v2 * v2 + v3 * v3;
        }
        lsum += __shfl_xor(lsum, 16, 64);
        lsum += __shfl_xor(lsum, 32, 64);
        lsq  += __shfl_xor(lsq, 16, 64);
        lsq  += __shfl_xor(lsq, 32, 64);
        if (lane < 16) { s_sum[ch][q] = lsum; s_sq[ch][q] = lsq; }
    }
    __syncthreads();
    if (tid < 32) {
        float ss = 0.f, sq = 0.f;
        #pragma unroll
        for (int j = 0; j < 3; ++j) {
            int ch = tid * 3 + j;
            ss += s_sum[ch][0] + s_sum[ch][1] + s_sum[ch][2] + s_sum[ch][3];
            sq += s_sq[ch][0] + s_sq[ch][1] + s_sq[ch][2] + s_sq[ch][3];
        }
        atomicAdd(&gnsum[b2 * 32 + tid], ss);
        atomicAdd(&gnsq [b2 * 32 + tid], sq);
    }
}

// ---- kD: agg = SiLU(BN2(sum_k GN(wd)*unfold(v))) -> bf16 aggh, + gap ----
// GN stats computed inline from gnsum/gnsq (kC2 folded in).
__global__ __launch_bounds__(256, 8) void kD_agg(
    const u16* __restrict__ wdh, const u16* __restrict__ vh,
    const float* __restrict__ gnsum, const float* __restrict__ gnsq,
    const float* __restrict__ gng, const float* __restrict__ gnb,
    const float* __restrict__ g, const float* __restrict__ bb,
    const float* __restrict__ m, const float* __restrict__ vr,
    u16* __restrict__ aggh, float* __restrict__ gap)
{
    int blk   = blockIdx.x;
    int strip = blk & 7;
    int c1    = (blk >> 3) & 31;
    int bi    = blk >> 8;
    int px0   = strip * 512 + threadIdx.x * 2;
    const float inv = 1.f / 12288.f;

    float sch[4], tch[4], gl[4];
    #pragma unroll
    for (int ch = 0; ch < 4; ++ch) {
        int c = c1 * 4 + ch;
        float s = g[c] * rsqrtf(vr[c] + EPSV);
        sch[ch] = s; tch[ch] = bb[c] - m[c] * s; gl[ch] = 0.f;
    }
    float gg[3], gb[3];
    #pragma unroll
    for (int k = 0; k < 3; ++k) { gg[k] = gng[c1 * 3 + k]; gb[k] = gnb[c1 * 3 + k]; }

    float2 vreg[4][3];
    #pragma unroll
    for (int ch = 0; ch < 4; ++ch) {
        vreg[ch][0] = make_float2(0.f, 0.f);
        u32 v1u = *(const u32*)(vh + ((bi * 8 + 0) * 128 + c1 * 4 + ch) * 4096 + px0);
        u32 v2u = *(const u32*)(vh + ((bi * 8 + 1) * 128 + c1 * 4 + ch) * 4096 + px0);
        vreg[ch][1] = make_float2(bflo(v1u), bfhi(v1u));
        vreg[ch][2] = make_float2(bflo(v2u), bfhi(v2u));
    }

    for (int ni = 0; ni < 8; ++ni) {
        int b2 = bi * 8 + ni;
        float mu = gnsum[b2 * 32 + c1] * inv;
        float var = fmaf(gnsq[b2 * 32 + c1], inv, -mu * mu);
        float rs = rsqrtf(fmaxf(var, 0.f) + EPSV);
        float2 wn[3];
        #pragma unroll
        for (int k = 0; k < 3; ++k) {
            int nf = ni + k - 1;
            if (nf >= 0 && nf < 8) {
                u32 wvu = *(const u32*)(wdh + ((b2 * 96 + c1 * 3 + k) * 4096 + px0));
                wn[k].x = fmaf((bflo(wvu) - mu) * rs, gg[k], gb[k]);
                wn[k].y = fmaf((bfhi(wvu) - mu) * rs, gg[k], gb[k]);
            } else {
                wn[k] = make_float2(0.f, 0.f);
            }
        }
        #pragma unroll
        for (int ch = 0; ch < 4; ++ch) {
            float a0 = 0.f, a1 = 0.f;
            #pragma unroll
            for (int k = 0; k < 3; ++k) {
                a0 = fmaf(wn[k].x, vreg[ch][k].x, a0);
                a1 = fmaf(wn[k].y, vreg[ch][k].y, a1);
            }
            float y0 = fmaf(a0, sch[ch], tch[ch]);
            float y1 = fmaf(a1, sch[ch], tch[ch]);
            float r0 = y0 / (1.f + __expf(-y0));
            float r1 = y1 / (1.f + __expf(-y1));
            *(u32*)(aggh + (b2 * 128 + c1 * 4 + ch) * 4096 + px0) =
                bfbits(r0) | (bfbits(r1) << 16);
            gl[ch] += r0 + r1;
        }
        if (ni < 7) {
            #pragma unroll
            for (int ch = 0; ch < 4; ++ch) {
                vreg[ch][0] = vreg[ch][1];
                vreg[ch][1] = vreg[ch][2];
                if (ni + 2 < 8) {
                    u32 vu = *(const u32*)(vh + ((bi * 8 + ni + 2) * 128 + c1 * 4 + ch) * 4096 + px0);
                    vreg[ch][2] = make_float2(bflo(vu), bfhi(vu));
                }
            }
        }
    }

    __shared__ float sm[4][4];
    int lane = threadIdx.x & 63, wid = threadIdx.x >> 6;
    #pragma unroll
    for (int ch = 0; ch < 4; ++ch) {
        float s = gl[ch];
        #pragma unroll
        for (int off = 32; off; off >>= 1) s += __shfl_down(s, off, 64);
        if (lane == 0) sm[ch][wid] = s;
    }
    __syncthreads();
    if (threadIdx.x < 4) {
        float* sr = sm[threadIdx.x];
        atomicAdd(&gap[bi * 128 + c1 * 4 + threadIdx.x], sr[0] + sr[1] + sr[2] + sr[3]);
    }
}

// ---- kE: SE head, merged (grid 4 = bi, 128 threads) ----
__global__ __launch_bounds__(128) void kE_attn(
    const float* __restrict__ gap,
    const float* __restrict__ w1, const float* __restrict__ b1,
    const float* __restrict__ g, const float* __restrict__ bb,
    const float* __restrict__ m, const float* __restrict__ vr,
    const float* __restrict__ w2, const float* __restrict__ b2v,
    float* __restrict__ attn)
{
    __shared__ float a_s[128];
    int bi = blockIdx.x;
    int oc = threadIdx.x;
    float acc = b1[oc];
    const float* gp = gap + bi * 128;
    const float* wp = w1 + oc * 128;
    for (int c = 0; c < 128; c += 4) {
        const float4 w4 = *(const float4*)(wp + c);
        acc = fmaf(gp[c + 0] * (1.f / 32768.f), w4.x, acc);
        acc = fmaf(gp[c + 1] * (1.f / 32768.f), w4.y, acc);
        acc = fmaf(gp[c + 2] * (1.f / 32768.f), w4.z, acc);
        acc = fmaf(gp[c + 3] * (1.f / 32768.f), w4.w, acc);
    }
    float s = g[oc] * rsqrtf(vr[oc] + EPSV);
    a_s[oc] = fmaxf(fmaf(acc, s, bb[oc] - m[oc] * s), 0.f);
    __syncthreads();

    int cc = threadIdx.x;
    float l0 = b2v[cc * 2], l1 = b2v[cc * 2 + 1];
    const float* w0p = w2 + (cc * 2) * 128;
    const float* w1p = w2 + (cc * 2 + 1) * 128;
    for (int j = 0; j < 128; j += 4) {
        const float4 wa4 = *(const float4*)(w0p + j);
        const float4 wb4 = *(const float4*)(w1p + j);
        l0 = fmaf(a_s[j + 0], wa4.x, l0); l1 = fmaf(a_s[j + 0], wb4.x, l1);
        l0 = fmaf(a_s[j + 1], wa4.y, l0); l1 = fmaf(a_s[j + 1], wb4.y, l1);
        l0 = fmaf(a_s[j + 2], wa4.z, l0); l1 = fmaf(a_s[j + 2], wb4.z, l1);
        l0 = fmaf(a_s[j + 3], wa4.w, l0); l1 = fmaf(a_s[j + 3], wb4.w, l1);
    }
    float mx = fmaxf(l0, l1);
    float e0 = __expf(l0 - mx), e1 = __expf(l1 - mx);
    float inv = 1.f / (e0 + e1);
    attn[bi * 256 + cc * 2]     = e0 * inv;
    attn[bi * 256 + cc * 2 + 1] = e1 * inv;
}

// ---- kF: out = attn0*agg + attn1*k2d; block = (b2, c8, strip); thread = 4 px ----
__global__ __launch_bounds__(256, 8) void kF_out(
    float* __restrict__ out, const u16* __restrict__ aggh,
    const u32* __restrict__ k2dq, const float* __restrict__ attn)
{
    int blk   = blockIdx.x;
    int strip = blk & 3;
    int c8    = (blk >> 2) & 15;
    int b2    = blk >> 6;
    int bi    = b2 >> 3;
    int p     = strip * 1024 + threadIdx.x * 4;

    const u32* kp = k2dq + ((b2 * 16 + c8) * 4096 + p) * 4;
    uint4 kq[4];
    #pragma unroll
    for (int i = 0; i < 4; ++i) kq[i] = *(const uint4*)(kp + i * 4);

    #pragma unroll
    for (int j = 0; j < 8; ++j) {
        int ch = c8 * 8 + j;
        float a0 = attn[bi * 256 + ch * 2];
        float a1 = attn[bi * 256 + ch * 2 + 1];
        uint2 ag = *(const uint2*)(aggh + (b2 * 128 + ch) * 4096 + p);
        float av[4] = { bflo(ag.x), bfhi(ag.x), bflo(ag.y), bfhi(ag.y) };
        float4 r;
        u32 kd0 = (&kq[0].x)[j >> 1];
        u32 kd1 = (&kq[1].x)[j >> 1];
        u32 kd2 = (&kq[2].x)[j >> 1];
        u32 kd3 = (&kq[3].x)[j >> 1];
        float kv0 = (j & 1) ? bfhi(kd0) : bflo(kd0);
        float kv1 = (j & 1) ? bfhi(kd1) : bflo(kd1);
        float kv2 = (j & 1) ? bfhi(kd2) : bflo(kd2);
        float kv3 = (j & 1) ? bfhi(kd3) : bflo(kd3);
        r.x = fmaf(a0, av[0], a1 * kv0);
        r.y = fmaf(a0, av[1], a1 * kv1);
        r.z = fmaf(a0, av[2], a1 * kv2);
        r.w = fmaf(a0, av[3], a1 * kv3);
        *(float4*)(out + (b2 * 128 + ch) * 4096 + p) = r;
    }
}

extern "C" void kernel_launch(void* const* d_in, const int* in_sizes, int n_in,
                              void* d_out, int out_size, void* d_ws, size_t ws_size,
                              hipStream_t stream)
{
    const float* x      = (const float*)d_in[0];
    const float* w_key  = (const float*)d_in[1];
    const float* bnk_g  = (const float*)d_in[2];
    const float* bnk_b  = (const float*)d_in[3];
    const float* bnk_m  = (const float*)d_in[4];
    const float* bnk_v  = (const float*)d_in[5];
    const float* w_e1   = (const float*)d_in[6];
    const float* bne_g  = (const float*)d_in[7];
    const float* bne_b  = (const float*)d_in[8];
    const float* bne_m  = (const float*)d_in[9];
    const float* bne_v  = (const float*)d_in[10];
    const float* w_e2   = (const float*)d_in[11];
    const float* b_e2   = (const float*)d_in[12];
    const float* gn_g   = (const float*)d_in[13];
    const float* gn_b   = (const float*)d_in[14];
    const float* w_1x1  = (const float*)d_in[15];
    const float* bn1_g  = (const float*)d_in[16];
    const float* bn1_b  = (const float*)d_in[17];
    const float* bn1_m  = (const float*)d_in[18];
    const float* bn1_v  = (const float*)d_in[19];
    const float* bn2_g  = (const float*)d_in[20];
    const float* bn2_b  = (const float*)d_in[21];
    const float* bn2_m  = (const float*)d_in[22];
    const float* bn2_v  = (const float*)d_in[23];
    const float* w_se1  = (const float*)d_in[24];
    const float* b_se1  = (const float*)d_in[25];
    const float* bnse_g = (const float*)d_in[26];
    const float* bnse_b = (const float*)d_in[27];
    const float* bnse_m = (const float*)d_in[28];
    const float* bnse_v = (const float*)d_in[29];
    const float* w_se2  = (const float*)d_in[30];
    const float* b_se2  = (const float*)d_in[31];

    float* ws    = (float*)d_ws;
    u32*  xq    = (u32*)ws;
    u32*  k2dq  = (u32*)(ws + 8388608);
    u16*  vh    = (u16*)(ws + 16777216);
    u16*  aggh  = (u16*)(ws + 25165824);
    u16*  wdh   = (u16*)(ws + 33554432);
    u32*  wkF   = (u32*)(ws + 39845888);
    u32*  wB1   = wkF + 6144;
    u32*  wB    = wB1 + 8192;
    u32*  wB2   = wB + 8192;
    float* st   = ws + 46137344;
    float* gnsum  = st;
    float* gnsq   = st + 1024;
    float* gap    = st + 2048;
    float* attn   = st + 4608;

    kXW_cvt<<<8192, 256, 0, stream>>>(x, xq, w_key, w_1x1, w_e1, w_e2,
                                      wkF, wB1, wB, wB2, gnsum);
    kA_key<<<2048, 256, 0, stream>>>(xq, wkF, bnk_g, bnk_b, bnk_m, bnk_v, k2dq, gap);
    kB_val<<<1024, 256, 0, stream>>>(xq, wB1, bn1_g, bn1_b, bn1_m, bn1_v, vh);
    kC_wd<<<1024, 256, 0, stream>>>(xq, k2dq, wB, bne_g, bne_b, bne_m, bne_v,
                                    wB2, b_e2, wdh, gnsum, gnsq);
    kD_agg<<<1024, 256, 0, stream>>>(wdh, vh, gnsum, gnsq, gn_g, gn_b,
                                     bn2_g, bn2_b, bn2_m, bn2_v, aggh, gap);
    kE_attn<<<4, 128, 0, stream>>>(gap, w_se1, b_se1, bnse_g, bnse_b, bnse_m, bnse_v,
                                   w_se2, b_se2, attn);
    kF_out<<<2048, 256, 0, stream>>>((float*)d_out, aggh, k2dq, attn);
}